// Round 6
// baseline (282.375 us; speedup 1.0000x reference)
//
#include <hip/hip_runtime.h>

typedef __attribute__((ext_vector_type(4))) float f32x4;
typedef __attribute__((ext_vector_type(8))) short bf16x8;
typedef unsigned short USHORT;

static __device__ __forceinline__ float bf2f(USHORT u) {
    return __uint_as_float(((unsigned)u) << 16);
}
static __device__ __forceinline__ USHORT f2bf(float f) {
    unsigned u = __float_as_uint(f);
    unsigned r = u + 0x7FFF + ((u >> 16) & 1);   // RTNE
    return (USHORT)(r >> 16);
}

// ---------------------------------------------------------------------------
// Weight transpose + cast: W fp32 [K=1024, N=1024] -> WT bf16 [N,K], 5 mats
// ---------------------------------------------------------------------------
struct TWArgs { const float* src[5]; USHORT* dst[5]; };

__global__ __launch_bounds__(256) void k_transpose_w(TWArgs ta) {
    const float* __restrict__ W  = ta.src[blockIdx.z];
    USHORT* __restrict__      WT = ta.dst[blockIdx.z];
    __shared__ USHORT t[64][65];
    const int k0 = blockIdx.y * 64, n0 = blockIdx.x * 64;
    const int tid = threadIdx.x;
#pragma unroll
    for (int s = 0; s < 4; s++) {
        int slot = tid + s * 256;
        int row = slot >> 4, c4 = (slot & 15) * 4;      // row = k, c4 = n
        float4 vv = *(const float4*)&W[(size_t)(k0 + row) * 1024 + n0 + c4];
        t[row][c4 + 0] = f2bf(vv.x);
        t[row][c4 + 1] = f2bf(vv.y);
        t[row][c4 + 2] = f2bf(vv.z);
        t[row][c4 + 3] = f2bf(vv.w);
    }
    __syncthreads();
#pragma unroll
    for (int s = 0; s < 2; s++) {
        int slot = tid + s * 256;
        int n = slot >> 3, c8 = (slot & 7) * 8;         // n = row of WT, c8 = k
        USHORT tmp[8];
#pragma unroll
        for (int u = 0; u < 8; u++) tmp[u] = t[c8 + u][n];
        *(int4*)&WT[(size_t)(n0 + n) * 1024 + k0 + c8] = *(int4*)tmp;
    }
}

// ---------------------------------------------------------------------------
// GEMM: C[M,1024] = act(A[M,1024] @ W + bias) * scale, W given as WT[N,K] bf16.
// A is fp32 (a_fp32=1, converted during staging) or bf16.
// 128x128 tile, BK=32, 256 threads (4 waves, 2x2), 16x16x32 bf16 MFMA.
// mode 0: bf16 row-major store; mode 1: sigmoid bf16 store; mode 2: V stored
// transposed as VT[b,h,d,s]; mode 3: fp32 row-major store (final output).
// ---------------------------------------------------------------------------
struct GArgs {
    const void*   A;
    int           a_fp32;
    const USHORT* W[4];
    const float*  bias[4];
    void*         dst[4];
    USHORT*       dstv;       // VT output for mode 2
    float         scale[4];
    int           mode[4];
};

__global__ __launch_bounds__(256, 2) void k_gemm(GArgs ga) {
    const int z = blockIdx.z;
    const USHORT* __restrict__ BT = ga.W[z];
    __shared__ USHORT As[128 * 32];
    __shared__ USHORT Bs[128 * 32];
    const int tid = threadIdx.x;
    const int m0 = blockIdx.y * 128, n0 = blockIdx.x * 128;
    const int w = tid >> 6, l = tid & 63, lr = l & 15, q = l >> 4;
    const int wr = w >> 1, wc = w & 1;
    const int srow = tid >> 2, sco = (tid & 3) * 8;
    f32x4 acc[4][4] = {};
    for (int k0 = 0; k0 < 1024; k0 += 32) {
        USHORT a0[8], a1[8];
        if (ga.a_fp32) {
            const float* Af = (const float*)ga.A;
            float4 f0 = *(const float4*)&Af[(size_t)(m0 + srow) * 1024 + k0 + sco];
            float4 f1 = *(const float4*)&Af[(size_t)(m0 + srow) * 1024 + k0 + sco + 4];
            float4 f2 = *(const float4*)&Af[(size_t)(m0 + srow + 64) * 1024 + k0 + sco];
            float4 f3 = *(const float4*)&Af[(size_t)(m0 + srow + 64) * 1024 + k0 + sco + 4];
            a0[0]=f2bf(f0.x); a0[1]=f2bf(f0.y); a0[2]=f2bf(f0.z); a0[3]=f2bf(f0.w);
            a0[4]=f2bf(f1.x); a0[5]=f2bf(f1.y); a0[6]=f2bf(f1.z); a0[7]=f2bf(f1.w);
            a1[0]=f2bf(f2.x); a1[1]=f2bf(f2.y); a1[2]=f2bf(f2.z); a1[3]=f2bf(f2.w);
            a1[4]=f2bf(f3.x); a1[5]=f2bf(f3.y); a1[6]=f2bf(f3.z); a1[7]=f2bf(f3.w);
        } else {
            const USHORT* Ab = (const USHORT*)ga.A;
            *(int4*)a0 = *(const int4*)&Ab[(size_t)(m0 + srow) * 1024 + k0 + sco];
            *(int4*)a1 = *(const int4*)&Ab[(size_t)(m0 + srow + 64) * 1024 + k0 + sco];
        }
        int4 b0 = *(const int4*)&BT[(size_t)(n0 + srow) * 1024 + k0 + sco];
        int4 b1 = *(const int4*)&BT[(size_t)(n0 + srow + 64) * 1024 + k0 + sco];
        __syncthreads();
        *(int4*)&As[srow * 32 + sco] = *(int4*)a0;
        *(int4*)&As[(srow + 64) * 32 + sco] = *(int4*)a1;
        *(int4*)&Bs[srow * 32 + sco] = b0;
        *(int4*)&Bs[(srow + 64) * 32 + sco] = b1;
        __syncthreads();
        bf16x8 af[4], bfr[4];
#pragma unroll
        for (int mi = 0; mi < 4; mi++)
            af[mi] = *(const bf16x8*)&As[(wr * 64 + mi * 16 + lr) * 32 + q * 8];
#pragma unroll
        for (int ni = 0; ni < 4; ni++)
            bfr[ni] = *(const bf16x8*)&Bs[(wc * 64 + ni * 16 + lr) * 32 + q * 8];
#pragma unroll
        for (int mi = 0; mi < 4; mi++)
#pragma unroll
            for (int ni = 0; ni < 4; ni++)
                acc[mi][ni] = __builtin_amdgcn_mfma_f32_16x16x32_bf16(
                    af[mi], bfr[ni], acc[mi][ni], 0, 0, 0);
    }
    const float scale = ga.scale[z];
    const int mode = ga.mode[z];
    const float* __restrict__ bias = ga.bias[z];
#pragma unroll
    for (int ni = 0; ni < 4; ni++) {
        int col = n0 + wc * 64 + ni * 16 + lr;          // D col = lane&15 (B free)
        float bv = bias[col];
#pragma unroll
        for (int mi = 0; mi < 4; mi++) {
            int r0 = m0 + wr * 64 + mi * 16 + q * 4;    // D row = quad*4+reg (A free)
            float vr[4];
#pragma unroll
            for (int r = 0; r < 4; r++) {
                float v = acc[mi][ni][r] + bv;
                if (mode == 1) v = 1.0f / (1.0f + __expf(-v));
                vr[r] = v * scale;
            }
            if (mode == 3) {
                float* df = (float*)ga.dst[z];
#pragma unroll
                for (int r = 0; r < 4; r++)
                    df[(size_t)(r0 + r) * 1024 + col] = vr[r];
            } else if (mode == 2) {
                // V[b,s,h*64+d] -> VT[((b*16+h)*64+d)*2048 + s], 4 consecutive s
                int b = r0 >> 11, s = r0 & 2047;
                int h = col >> 6, d = col & 63;
                *(ushort4*)&ga.dstv[(size_t)(((b * 16 + h) * 64) + d) * 2048 + s] =
                    make_ushort4(f2bf(vr[0]), f2bf(vr[1]), f2bf(vr[2]), f2bf(vr[3]));
            } else {
                USHORT* db = (USHORT*)ga.dst[z];
#pragma unroll
                for (int r = 0; r < 4; r++)
                    db[(size_t)(r0 + r) * 1024 + col] = f2bf(vr[r]);
            }
        }
    }
}

// ---------------------------------------------------------------------------
// Attention: per (b,h): Pt = K Q^T (Q pre-scaled by 1/8), decay+causal mask,
// retained^T = VT Pt. Block: 128 i-rows, 4 waves x 32i. R written bf16.
// ---------------------------------------------------------------------------
__global__ __launch_bounds__(256, 2) void k_attn(const USHORT* __restrict__ Q,
                                                 const USHORT* __restrict__ K,
                                                 const USHORT* __restrict__ VT,
                                                 USHORT* __restrict__ R) {
    const int bh = blockIdx.x;
    const int b = bh >> 4, h = bh & 15;
    const int rr = blockIdx.y;
    const int iblk = (rr < 8) ? rr : 23 - rr;   // pair heavy+light across CUs
    const int i0 = iblk * 128;
    const int tid = threadIdx.x, w = tid >> 6, l = tid & 63, lr = l & 15, q = l >> 4;
    __shared__ USHORT Qs[128 * 64];
    __shared__ USHORT Ks[64 * 64];
    __shared__ USHORT Vs[64 * 64];
    __shared__ USHORT Ps[4][32 * 64];
#pragma unroll
    for (int s = 0; s < 4; s++) {
        int slot = tid + s * 256;
        int rw = slot >> 3, c8 = (slot & 7) * 8;
        *(int4*)&Qs[rw * 64 + c8] =
            *(const int4*)&Q[(size_t)(b * 2048 + i0 + rw) * 1024 + h * 64 + c8];
    }
    const int iw0 = i0 + w * 32;
    const float L2D = -0.014499569695115089f;   // log2(0.99)
    f32x4 accr[4][2] = {};
    const int njb = iblk * 2 + 2;
    for (int jb = 0; jb < njb; jb++) {
        const int j0 = jb * 64;
        {   // stage K tile [64j x 64d] and VT tile [64d x 64j]
            int r0_ = tid >> 3, c0 = (tid & 7) * 8;
            int slot1 = tid + 256;
            int r1_ = slot1 >> 3, c1 = (slot1 & 7) * 8;
            int4 kv0 = *(const int4*)&K[(size_t)(b * 2048 + j0 + r0_) * 1024 + h * 64 + c0];
            int4 kv1 = *(const int4*)&K[(size_t)(b * 2048 + j0 + r1_) * 1024 + h * 64 + c1];
            int4 vv0 = *(const int4*)&VT[(size_t)(bh * 64 + r0_) * 2048 + j0 + c0];
            int4 vv1 = *(const int4*)&VT[(size_t)(bh * 64 + r1_) * 2048 + j0 + c1];
            __syncthreads();
            *(int4*)&Ks[r0_ * 64 + c0] = kv0;
            *(int4*)&Ks[r1_ * 64 + c1] = kv1;
            *(int4*)&Vs[r0_ * 64 + c0] = vv0;
            *(int4*)&Vs[r1_ * 64 + c1] = vv1;
            __syncthreads();
        }
        if (j0 <= iw0 + 31) {
            // Pt[64j x 32i] = K Q^T : D row=j (quad*4+reg), col=i (lane&15)
            f32x4 accp[4][2] = {};
#pragma unroll
            for (int kk = 0; kk < 2; kk++) {
                bf16x8 bqf[2];
#pragma unroll
                for (int it = 0; it < 2; it++)
                    bqf[it] = *(const bf16x8*)&Qs[(w * 32 + it * 16 + lr) * 64 + kk * 32 + q * 8];
#pragma unroll
                for (int jt = 0; jt < 4; jt++) {
                    bf16x8 akf = *(const bf16x8*)&Ks[(jt * 16 + lr) * 64 + kk * 32 + q * 8];
#pragma unroll
                    for (int it = 0; it < 2; it++)
                        accp[jt][it] = __builtin_amdgcn_mfma_f32_16x16x32_bf16(
                            akf, bqf[it], accp[jt][it], 0, 0, 0);
                }
            }
            // decay + causal mask, direct per element: P *= 0.99^(i-j), 0 if j>i
#pragma unroll
            for (int jt = 0; jt < 4; jt++) {
#pragma unroll
                for (int it = 0; it < 2; it++) {
                    const int ii = iw0 + it * 16 + lr;
                    USHORT pk[4];
#pragma unroll
                    for (int r = 0; r < 4; r++) {
                        int jj = j0 + jt * 16 + q * 4 + r;
                        float v = (jj <= ii)
                            ? accp[jt][it][r] * exp2f(L2D * (float)(ii - jj))
                            : 0.0f;
                        pk[r] = f2bf(v);
                    }
                    *(ushort4*)&Ps[w][(it * 16 + lr) * 64 + jt * 16 + q * 4] =
                        make_ushort4(pk[0], pk[1], pk[2], pk[3]);
                }
            }
            // within-wave LDS RAW fence (Ps write -> Ps read)
            asm volatile("s_waitcnt lgkmcnt(0)" ::: "memory");
            // retained^T[64d x 32i] += VT_tile * Pt
#pragma unroll
            for (int kk = 0; kk < 2; kk++) {
                bf16x8 bpf[2];
#pragma unroll
                for (int it = 0; it < 2; it++)
                    bpf[it] = *(const bf16x8*)&Ps[w][(it * 16 + lr) * 64 + kk * 32 + q * 8];
#pragma unroll
                for (int dt = 0; dt < 4; dt++) {
                    bf16x8 avf = *(const bf16x8*)&Vs[(dt * 16 + lr) * 64 + kk * 32 + q * 8];
#pragma unroll
                    for (int it = 0; it < 2; it++)
                        accr[dt][it] = __builtin_amdgcn_mfma_f32_16x16x32_bf16(
                            avf, bpf[it], accr[dt][it], 0, 0, 0);
                }
            }
        }
    }
#pragma unroll
    for (int it = 0; it < 2; it++) {
        int i = i0 + w * 32 + it * 16 + lr;
#pragma unroll
        for (int dt = 0; dt < 4; dt++) {
            f32x4 a = accr[dt][it];
            *(ushort4*)&R[(size_t)(b * 2048 + i) * 1024 + h * 64 + dt * 16 + q * 4] =
                make_ushort4(f2bf(a[0]), f2bf(a[1]), f2bf(a[2]), f2bf(a[3]));
        }
    }
}

// ---------------------------------------------------------------------------
// LayerNorm over D=1024 (R bf16) + gate multiply. One block per row.
// ---------------------------------------------------------------------------
__global__ __launch_bounds__(256) void k_ln_gate(const USHORT* __restrict__ R,
                                                 const USHORT* __restrict__ G,
                                                 const float* __restrict__ gamma,
                                                 const float* __restrict__ beta,
                                                 USHORT* __restrict__ NG) {
    const int row = blockIdx.x, tid = threadIdx.x;
    ushort4 rv = *(const ushort4*)&R[(size_t)row * 1024 + tid * 4];
    float vv[4] = { bf2f(rv.x), bf2f(rv.y), bf2f(rv.z), bf2f(rv.w) };
    float s  = vv[0] + vv[1] + vv[2] + vv[3];
    float s2 = vv[0]*vv[0] + vv[1]*vv[1] + vv[2]*vv[2] + vv[3]*vv[3];
#pragma unroll
    for (int o = 32; o > 0; o >>= 1) {
        s  += __shfl_down(s, o, 64);
        s2 += __shfl_down(s2, o, 64);
    }
    __shared__ float red[8];
    if ((tid & 63) == 0) { red[tid >> 6] = s; red[4 + (tid >> 6)] = s2; }
    __syncthreads();
    const float ts  = red[0] + red[1] + red[2] + red[3];
    const float ts2 = red[4] + red[5] + red[6] + red[7];
    const float mu  = ts * (1.0f / 1024.0f);
    const float var = ts2 * (1.0f / 1024.0f) - mu * mu;
    const float inv = rsqrtf(var + 1e-5f);
    ushort4 g4 = *(const ushort4*)&G[(size_t)row * 1024 + tid * 4];
    float4 gm = *(const float4*)&gamma[tid * 4];
    float4 bt = *(const float4*)&beta[tid * 4];
    USHORT gg[4]  = { g4.x, g4.y, g4.z, g4.w };
    float  gmm[4] = { gm.x, gm.y, gm.z, gm.w };
    float  btt[4] = { bt.x, bt.y, bt.z, bt.w };
    USHORT o4[4];
#pragma unroll
    for (int u = 0; u < 4; u++) {
        float nv = (vv[u] - mu) * inv * gmm[u] + btt[u];
        o4[u] = f2bf(nv * bf2f(gg[u]));
    }
    *(ushort4*)&NG[(size_t)row * 1024 + tid * 4] = make_ushort4(o4[0], o4[1], o4[2], o4[3]);
}

// ---------------------------------------------------------------------------
extern "C" void kernel_launch(void* const* d_in, const int* in_sizes, int n_in,
                              void* d_out, int out_size, void* d_ws, size_t ws_size,
                              hipStream_t stream) {
    // Inputs fp32 (per reference dtypes). Output fp32 (reference returns fp32).
    const float* x     = (const float*)d_in[0];
    const float* Wq    = (const float*)d_in[1];
    const float* bq    = (const float*)d_in[2];
    const float* Wk    = (const float*)d_in[3];
    const float* bk    = (const float*)d_in[4];
    const float* Wv    = (const float*)d_in[5];
    const float* bv    = (const float*)d_in[6];
    const float* Wg    = (const float*)d_in[7];
    const float* bg    = (const float*)d_in[8];
    const float* Wo    = (const float*)d_in[9];
    const float* bo    = (const float*)d_in[10];
    const float* gamma = (const float*)d_in[11];
    const float* beta  = (const float*)d_in[12];

    // Workspace: 42 MB.
    char* ws = (char*)d_ws;
    const size_t MB = 1 << 20;
    USHORT* WqT = (USHORT*)(ws + 0 * MB);
    USHORT* WkT = (USHORT*)(ws + 2 * MB);
    USHORT* WvT = (USHORT*)(ws + 4 * MB);
    USHORT* WgT = (USHORT*)(ws + 6 * MB);
    USHORT* WoT = (USHORT*)(ws + 8 * MB);
    USHORT* Qb  = (USHORT*)(ws + 10 * MB);
    USHORT* Kb  = (USHORT*)(ws + 18 * MB);
    USHORT* VTb = (USHORT*)(ws + 26 * MB);
    USHORT* Gb  = (USHORT*)(ws + 34 * MB);
    USHORT* NGb = Qb;                 // Qb dead after attention
    USHORT* Rb  = (USHORT*)d_out;     // bf16 scratch in fp32 d_out (16 MB);
                                      // fully overwritten by the final fp32 GEMM

    {   // transpose+cast all 5 weights to bf16 [N,K]
        TWArgs ta;
        ta.src[0] = Wq; ta.src[1] = Wk; ta.src[2] = Wv; ta.src[3] = Wg; ta.src[4] = Wo;
        ta.dst[0] = WqT; ta.dst[1] = WkT; ta.dst[2] = WvT; ta.dst[3] = WgT; ta.dst[4] = WoT;
        k_transpose_w<<<dim3(16, 16, 5), 256, 0, stream>>>(ta);
    }
    {   // 4 fused projections from fp32 x: Q (scaled 1/8), K, V (transposed), G (sigmoid)
        GArgs ga;
        ga.A = (const void*)x; ga.a_fp32 = 1;
        ga.W[0] = WqT; ga.W[1] = WkT; ga.W[2] = WvT; ga.W[3] = WgT;
        ga.bias[0] = bq; ga.bias[1] = bk; ga.bias[2] = bv; ga.bias[3] = bg;
        ga.dst[0] = Qb; ga.dst[1] = Kb; ga.dst[2] = nullptr; ga.dst[3] = Gb;
        ga.dstv = VTb;
        ga.scale[0] = 0.125f; ga.scale[1] = 1.0f; ga.scale[2] = 1.0f; ga.scale[3] = 1.0f;
        ga.mode[0] = 0; ga.mode[1] = 0; ga.mode[2] = 2; ga.mode[3] = 1;
        k_gemm<<<dim3(8, 32, 4), 256, 0, stream>>>(ga);
    }
    k_attn<<<dim3(32, 16), 256, 0, stream>>>(Qb, Kb, VTb, Rb);
    k_ln_gate<<<4096, 256, 0, stream>>>(Rb, Gb, gamma, beta, NGb);
    {   // output projection -> d_out as FP32 (mode 3), overwrites Rb scratch
        GArgs go;
        go.A = (const void*)NGb; go.a_fp32 = 0;
        for (int i = 0; i < 4; i++) {
            go.W[i] = WoT; go.bias[i] = bo; go.dst[i] = d_out;
            go.scale[i] = 1.0f; go.mode[i] = 3;
        }
        go.dstv = nullptr;
        k_gemm<<<dim3(8, 32, 1), 256, 0, stream>>>(go);
    }
}